// Round 7
// baseline (265.344 us; speedup 1.0000x reference)
//
#include <hip/hip_runtime.h>

#define N 3072
#define D_IN 64
#define HID 128
#define NH 4
#define HD 32
#define NB 1024
#define ALPHA 0.2f
#define TD 0.1f
#define EPS 1e-5f
#define LOG2E 1.4426950408889634f
#define TSPLIT 16
#define JSPAN (N / TSPLIT)  /* 192 */
#define NCH (JSPAN / 64)    /* 3   */
#define PSTR 72             /* padded bf16 row stride for p tiles */

typedef unsigned int uint;
typedef unsigned short ushort;
typedef __attribute__((ext_vector_type(8))) __bf16 bf16x8;
typedef __attribute__((ext_vector_type(4))) float f32x4;

__device__ __forceinline__ ushort f2bf(float f) {
  union { float f; uint u; } c; c.f = f;
  uint u = c.u;
  return (ushort)((u + 0x7FFFu + ((u >> 16) & 1u)) >> 16);
}

// ---------------- prep: row max of tmat -> global atomicMax; adj row sum -> deg0 ----------------
__global__ __launch_bounds__(256) void k_prep(const float* __restrict__ tmat,
                                              const float* __restrict__ adj,
                                              uint* __restrict__ tmax_u,
                                              uint* __restrict__ deg0) {
  int row = blockIdx.x * 4 + (threadIdx.x >> 6);
  int lane = threadIdx.x & 63;
  const float4* tr = (const float4*)(tmat + (size_t)row * N);
  const float4* ar = (const float4*)(adj + (size_t)row * N);
  float mx = 0.f, s = 0.f;
#pragma unroll
  for (int it = 0; it < 12; it++) {
    float4 t4 = tr[lane + it * 64];
    float4 a4 = ar[lane + it * 64];
    mx = fmaxf(mx, fmaxf(fmaxf(t4.x, t4.y), fmaxf(t4.z, t4.w)));
    s += a4.x + a4.y + a4.z + a4.w;
  }
  for (int o = 32; o > 0; o >>= 1) { mx = fmaxf(mx, __shfl_xor(mx, o)); s += __shfl_xor(s, o); }
  __shared__ float smx[4];
  int w = threadIdx.x >> 6;
  if (lane == 0) { deg0[row] = (s == 0.f) ? 1u : 0u; smx[w] = mx; }
  __syncthreads();
  if (threadIdx.x == 0) {
    float m = fmaxf(fmaxf(smx[0], smx[1]), fmaxf(smx[2], smx[3]));
    atomicMax(tmax_u, __float_as_uint(m));
  }
}

// ---------------- fused x-build + h GEMM + es/ed + hT  ----------------
// layer==0: x = emb@Ws+bs (struct).  layer==1: x = LN(ELU(o/s)) (combine of layer 0).
__global__ __launch_bounds__(256) void k_hx(int layer,
                                            const float* __restrict__ emb,
                                            const float* __restrict__ Ws,
                                            const float* __restrict__ bs,
                                            const float* __restrict__ o_part,
                                            const float* __restrict__ s_part,
                                            const float* __restrict__ lg,
                                            const float* __restrict__ lb,
                                            const float* __restrict__ gW,
                                            const float* __restrict__ gA,
                                            ushort* __restrict__ hT,
                                            float* __restrict__ es,
                                            float* __restrict__ ed) {
  int n0 = blockIdx.x * 8;
  int t = threadIdx.x;
  __shared__ float xs[8][HID];
  __shared__ float hs[8][HID];
  __shared__ float embs[8][D_IN];

  if (layer == 0) {
    for (int k = t; k < 8 * D_IN; k += 256) embs[k >> 6][k & 63] = emb[n0 * D_IN + k];
    __syncthreads();
    int c = t & 127, rh = t >> 7;
#pragma unroll
    for (int k = 0; k < 4; k++) {
      int r = rh + 2 * k;
      float acc = bs[c];
#pragma unroll
      for (int i = 0; i < D_IN; i++) acc += embs[r][i] * Ws[i * HID + c];
      xs[r][c] = acc;
    }
  } else {
    // combine: wave w handles rows 2w, 2w+1; lane l handles cols 2l, 2l+1
    int w = t >> 6, l = t & 63;
    int h = l >> 4;
#pragma unroll
    for (int rr = 0; rr < 2; rr++) {
      int i = n0 + 2 * w + rr;
      float ox = 0.f, oy = 0.f, sden = 0.f;
#pragma unroll
      for (int sp = 0; sp < TSPLIT; sp++) {
        float2 ov = *(const float2*)&o_part[((size_t)sp * N + i) * HID + 2 * l];
        ox += ov.x; oy += ov.y;
        sden += s_part[((size_t)sp * N + i) * NH + h];
      }
      float v0 = ox / sden, v1 = oy / sden;
      v0 = v0 > 0.f ? v0 : expm1f(v0);
      v1 = v1 > 0.f ? v1 : expm1f(v1);
      float sm = v0 + v1, sq = v0 * v0 + v1 * v1;
      for (int o = 32; o > 0; o >>= 1) { sm += __shfl_xor(sm, o); sq += __shfl_xor(sq, o); }
      float mu = sm / (float)HID;
      float var = sq / (float)HID - mu * mu;
      float rs = rsqrtf(var + EPS);
      xs[2 * w + rr][2 * l]     = (v0 - mu) * rs * lg[2 * l]     + lb[2 * l];
      xs[2 * w + rr][2 * l + 1] = (v1 - mu) * rs * lg[2 * l + 1] + lb[2 * l + 1];
    }
  }
  __syncthreads();

  // ---- common: h = xs @ gW per head ----
  int c = t & 127, rh = t >> 7;
  const float* Wc = gW + (c >> 5) * (HID * HD) + (c & 31);
  float acc[4] = {0.f, 0.f, 0.f, 0.f};
  for (int i = 0; i < HID; i++) {
    float wv = Wc[i * HD];
#pragma unroll
    for (int r4 = 0; r4 < 4; r4++) acc[r4] += xs[rh + 2 * r4][i] * wv;
  }
#pragma unroll
  for (int r4 = 0; r4 < 4; r4++) hs[rh + 2 * r4][c] = acc[r4];
  __syncthreads();
  if (t < 64) {
    int r = t >> 3, h_ = (t >> 1) & 3, sd = t & 1;
    const float* av = gA + h_ * (2 * HD) + sd * HD;
    float d = 0.f;
#pragma unroll
    for (int k = 0; k < HD; k++) d += hs[r][h_ * HD + k] * av[k];
    (sd ? ed : es)[h_ * N + n0 + r] = d;
  }
  {
    int half = t >> 7;
    ushort pk[4];
#pragma unroll
    for (int r = 0; r < 4; r++) pk[r] = f2bf(hs[half * 4 + r][c]);
    uint2 v;
    v.x = (uint)pk[0] | ((uint)pk[1] << 16);
    v.y = (uint)pk[2] | ((uint)pk[3] << 16);
    *(uint2*)(&hT[(size_t)c * N + n0 + half * 4]) = v;
  }
}

// ---------------- fused score + PV: direct tmat/adj reads, 32 rows/block, dbuf ----------------
__global__ __launch_bounds__(256) void k_att(const float* __restrict__ tmat,
                                             const float* __restrict__ adj,
                                             const uint* __restrict__ tmax_u,
                                             const ushort* __restrict__ hT,
                                             const float* __restrict__ es,
                                             const float* __restrict__ ed,
                                             const uint* __restrict__ deg0,
                                             float* __restrict__ o_part,
                                             float* __restrict__ s_part) {
  __shared__ __align__(16) ushort ps[2][NH][32][PSTR];
  int tid = threadIdx.x;
  int ib = blockIdx.x * 32;
  int sp = blockIdx.y;
  int jb0 = sp * JSPAN;
  float tmax = __uint_as_float(*tmax_u);
  const float c1 = TD * LOG2E;

  int jl = tid & 31;
  int ig = tid >> 5;
  float esr[4][NH];
  uint dg[4];
#pragma unroll
  for (int p = 0; p < 4; p++) {
    int i = ib + ig + 8 * p;
    dg[p] = deg0[i];
#pragma unroll
    for (int h_ = 0; h_ < NH; h_++) esr[p][h_] = es[h_ * N + i];
  }

  int wv = tid >> 6;
  int ln = tid & 63;
  f32x4 acc00 = {0.f, 0.f, 0.f, 0.f}, acc01 = {0.f, 0.f, 0.f, 0.f};
  f32x4 acc10 = {0.f, 0.f, 0.f, 0.f}, acc11 = {0.f, 0.f, 0.f, 0.f};
  float sacc[4][NH];
#pragma unroll
  for (int p = 0; p < 4; p++)
#pragma unroll
    for (int h_ = 0; h_ < NH; h_++) sacc[p][h_] = 0.f;

  float2 t2v[4], a2v[4], edv[NH];

  auto LOADS = [&](int ch) {
    int j0 = jb0 + ch * 64 + 2 * jl;
#pragma unroll
    for (int p = 0; p < 4; p++) {
      t2v[p] = *(const float2*)&tmat[(size_t)(ib + ig + 8 * p) * N + j0];
      a2v[p] = *(const float2*)&adj[(size_t)(ib + ig + 8 * p) * N + j0];
    }
#pragma unroll
    for (int h_ = 0; h_ < NH; h_++) edv[h_] = *(const float2*)&ed[h_ * N + j0];
  };
  auto COMPUTE = [&](int buf) {
#pragma unroll
    for (int p = 0; p < 4; p++) {
      float m0 = __builtin_amdgcn_exp2f(c1 * (t2v[p].x - tmax)) * LOG2E;
      float m1 = __builtin_amdgcn_exp2f(c1 * (t2v[p].y - tmax)) * LOG2E;
      bool z0 = (a2v[p].x != 0.f), z1 = (a2v[p].y != 0.f);
#pragma unroll
      for (int h_ = 0; h_ < NH; h_++) {
        float e0 = esr[p][h_] + edv[h_].x;
        float e1 = esr[p][h_] + edv[h_].y;
        float l0 = fmaxf(e0, 0.f) + ALPHA * fminf(e0, 0.f);
        float l1 = fmaxf(e1, 0.f) + ALPHA * fminf(e1, 0.f);
        float p0 = __builtin_amdgcn_exp2f(l0 * m0);
        float p1 = __builtin_amdgcn_exp2f(l1 * m1);
        p0 = z0 ? p0 : 0.f;
        p1 = z1 ? p1 : 0.f;
        if (dg[p]) { p0 = 1.f; p1 = 1.f; }
        sacc[p][h_] += p0 + p1;
        uint pk = (__float_as_uint(p0) >> 16) | (__float_as_uint(p1) & 0xFFFF0000u);
        *(uint*)&ps[buf][h_][ig + 8 * p][2 * jl] = pk;
      }
    }
  };

  LOADS(0);
  COMPUTE(0);

  int r = ln & 15, g = ln >> 4;
  for (int ch = 0; ch < NCH; ch++) {
    __syncthreads();
    if (ch + 1 < NCH) LOADS(ch + 1);
    {
      int jb = jb0 + ch * 64;
      const ushort* hTb = hT + (size_t)(wv * HD) * N + jb;
      int buf = ch & 1;
#pragma unroll
      for (int ks = 0; ks < 2; ks++) {
        bf16x8 a0f = *(const bf16x8*)&ps[buf][wv][r][ks * 32 + g * 8];
        bf16x8 a1f = *(const bf16x8*)&ps[buf][wv][16 + r][ks * 32 + g * 8];
        bf16x8 b0 = *(const bf16x8*)(hTb + (size_t)r * N + ks * 32 + g * 8);
        bf16x8 b1 = *(const bf16x8*)(hTb + (size_t)(16 + r) * N + ks * 32 + g * 8);
        acc00 = __builtin_amdgcn_mfma_f32_16x16x32_bf16(a0f, b0, acc00, 0, 0, 0);
        acc01 = __builtin_amdgcn_mfma_f32_16x16x32_bf16(a0f, b1, acc01, 0, 0, 0);
        acc10 = __builtin_amdgcn_mfma_f32_16x16x32_bf16(a1f, b0, acc10, 0, 0, 0);
        acc11 = __builtin_amdgcn_mfma_f32_16x16x32_bf16(a1f, b1, acc11, 0, 0, 0);
      }
    }
    if (ch + 1 < NCH) COMPUTE((ch + 1) & 1);
  }

#pragma unroll
  for (int p = 0; p < 4; p++)
#pragma unroll
    for (int h_ = 0; h_ < NH; h_++) {
      float v = sacc[p][h_];
      v += __shfl_xor(v, 16); v += __shfl_xor(v, 8);
      v += __shfl_xor(v, 4);  v += __shfl_xor(v, 2); v += __shfl_xor(v, 1);
      if (jl == 0) {
        int i = ib + ig + 8 * p;
        s_part[((size_t)sp * N + i) * NH + h_] = v;
      }
    }
  {
#pragma unroll
    for (int q = 0; q < 4; q++) {
      int i0 = ib + g * 4 + q;
      int i1 = ib + 16 + g * 4 + q;
      float* op0 = o_part + ((size_t)sp * N + i0) * HID + wv * HD;
      float* op1 = o_part + ((size_t)sp * N + i1) * HID + wv * HD;
      op0[r] = acc00[q];
      op0[16 + r] = acc01[q];
      op1[r] = acc10[q];
      op1[16 + r] = acc11[q];
    }
  }
}

// ---------------- final: combine(layer1) for gathered row + MLP ----------------
__global__ __launch_bounds__(128) void k_final(const float* __restrict__ o_part,
                                               const float* __restrict__ s_part,
                                               const float* __restrict__ lg,
                                               const float* __restrict__ lb,
                                               const int* __restrict__ tid,
                                               const float* __restrict__ attr,
                                               const float* __restrict__ Wa,
                                               const float* __restrict__ ba,
                                               const float* __restrict__ W1,
                                               const float* __restrict__ b1,
                                               const float* __restrict__ W2,
                                               const float* __restrict__ b2,
                                               float* __restrict__ out) {
  int bI = blockIdx.x, c = threadIdx.x;
  __shared__ float tf[HID];
  __shared__ float s2[2][2];
  __shared__ float red[2];
  int id = tid[bI];
  float av = attr[bI];
  float o = 0.f, sden = 0.f;
  int h = c >> 5;
#pragma unroll
  for (int sp = 0; sp < TSPLIT; sp++) {
    o += o_part[((size_t)sp * N + id) * HID + c];
    sden += s_part[((size_t)sp * N + id) * NH + h];
  }
  float v = o / sden;
  v = v > 0.f ? v : expm1f(v);
  float sm = v, sq = v * v;
  for (int off = 32; off > 0; off >>= 1) { sm += __shfl_xor(sm, off); sq += __shfl_xor(sq, off); }
  int w = c >> 6, l = c & 63;
  if (l == 0) { s2[w][0] = sm; s2[w][1] = sq; }
  __syncthreads();
  float tot = s2[0][0] + s2[1][0], totq = s2[0][1] + s2[1][1];
  float mu = tot / (float)HID;
  float var = totq / (float)HID - mu * mu;
  float rs = rsqrtf(var + EPS);
  tf[c] = (v - mu) * rs * lg[c] + lb[c] + av * Wa[c] + ba[c];
  __syncthreads();
  float acc = b1[c];
  for (int i = 0; i < HID; i++) acc += tf[i] * W1[i * HID + c];
  acc = fmaxf(acc, 0.f);
  float pr = acc * W2[c];
  for (int off = 32; off > 0; off >>= 1) pr += __shfl_xor(pr, off);
  if (l == 0) red[w] = pr;
  __syncthreads();
  if (c == 0) out[bI] = red[0] + red[1] + b2[0];
}

extern "C" void kernel_launch(void* const* d_in, const int* in_sizes, int n_in,
                              void* d_out, int out_size, void* d_ws, size_t ws_size,
                              hipStream_t stream) {
  (void)in_sizes; (void)n_in; (void)out_size; (void)ws_size;
  const int*   topic_ids = (const int*)d_in[0];
  const float* adj  = (const float*)d_in[1];
  const float* tmat = (const float*)d_in[2];
  const float* attr = (const float*)d_in[3];
  const float* emb  = (const float*)d_in[4];
  const float* Ws   = (const float*)d_in[5];
  const float* bs   = (const float*)d_in[6];
  const float* Wa   = (const float*)d_in[7];
  const float* ba   = (const float*)d_in[8];
  const float* gW   = (const float*)d_in[9];
  const float* gA   = (const float*)d_in[10];
  const float* lng  = (const float*)d_in[11];
  const float* lnb  = (const float*)d_in[12];
  const float* W1   = (const float*)d_in[13];
  const float* b1   = (const float*)d_in[14];
  const float* W2   = (const float*)d_in[15];
  const float* b2   = (const float*)d_in[16];

  char* ws = (char*)d_ws;
  size_t o = 0;
  auto alloc = [&](size_t bytes) { void* p = ws + o; o += (bytes + 255) & ~255ull; return p; };
  uint*   tmax_u = (uint*)alloc(4);
  uint*   deg0   = (uint*)alloc((size_t)N * 4);
  ushort* hT     = (ushort*)alloc((size_t)HID * N * 2);
  float*  es     = (float*)alloc((size_t)NH * N * 4);
  float*  ed     = (float*)alloc((size_t)NH * N * 4);
  float*  o_part = (float*)alloc((size_t)TSPLIT * N * HID * 4);
  float*  s_part = (float*)alloc((size_t)TSPLIT * N * NH * 4);

  hipMemsetAsync(tmax_u, 0, 4, stream);
  k_prep<<<N / 4, 256, 0, stream>>>(tmat, adj, tmax_u, deg0);

  dim3 gr(N / 32, TSPLIT);
  // layer 0
  k_hx<<<N / 8, 256, 0, stream>>>(0, emb, Ws, bs, nullptr, nullptr, nullptr, nullptr,
                                  gW, gA, hT, es, ed);
  k_att<<<gr, 256, 0, stream>>>(tmat, adj, tmax_u, hT, es, ed, deg0, o_part, s_part);
  // layer 1 (combine of layer 0 fused in)
  k_hx<<<N / 8, 256, 0, stream>>>(1, nullptr, nullptr, nullptr, o_part, s_part, lng, lnb,
                                  gW + (size_t)NH * HID * HD, gA + (size_t)NH * 2 * HD,
                                  hT, es, ed);
  k_att<<<gr, 256, 0, stream>>>(tmat, adj, tmax_u, hT, es, ed, deg0, o_part, s_part);
  // final (combine of layer 1 fused in)
  k_final<<<NB, 128, 0, stream>>>(o_part, s_part, lng + HID, lnb + HID,
                                  topic_ids, attr, Wa, ba, W1, b1, W2, b2, (float*)d_out);
}

// Round 9
// 220.362 us; speedup vs baseline: 1.2041x; 1.2041x over previous
//
#include <hip/hip_runtime.h>

#define N 3072
#define D_IN 64
#define HID 128
#define NH 4
#define HD 32
#define NB 1024
#define ALPHA 0.2f
#define TD 0.1f
#define EPS 1e-5f
#define LOG2E 1.4426950408889634f
#define TSPLIT 16
#define JSPAN (N / TSPLIT)  /* 192 */
#define NCH (JSPAN / 64)    /* 3   */
#define PSTR 72             /* padded bf16 row stride for p tiles */

typedef unsigned int uint;
typedef unsigned short ushort;
typedef __attribute__((ext_vector_type(8))) __bf16 bf16x8;
typedef __attribute__((ext_vector_type(4))) float f32x4;

__device__ __forceinline__ ushort f2bf(float f) {
  union { float f; uint u; } c; c.f = f;
  uint u = c.u;
  return (ushort)((u + 0x7FFFu + ((u >> 16) & 1u)) >> 16);
}
__device__ __forceinline__ float bf2f(ushort u) {
  union { uint u; float f; } c; c.u = ((uint)u) << 16;
  return c.f;
}

// ---- prep: rows 0..767: tmat row-max -> atomicMax, adj row-sum -> deg0.
// ---- blocks 768,769: transpose gat_W[l] -> WT[l][n][k] bf16 (for MFMA B-frags).
__global__ __launch_bounds__(256) void k_prep(const float* __restrict__ tmat,
                                              const float* __restrict__ adj,
                                              const float* __restrict__ gW,
                                              uint* __restrict__ tmax_u,
                                              uint* __restrict__ deg0,
                                              ushort* __restrict__ wt) {
  int t = threadIdx.x;
  if (blockIdx.x >= N / 4) {
    int l = blockIdx.x - N / 4;
    const float* gWl = gW + (size_t)l * NH * HID * HD;
    ushort* wtl = wt + (size_t)l * HID * HID;
    int n = t >> 1, k0 = (t & 1) * 64;
    int h = n >> 5, o = n & 31;
    const float* src = gWl + (size_t)h * (HID * HD) + o;
    ushort* dst = wtl + (size_t)n * HID + k0;
#pragma unroll
    for (int kk = 0; kk < 64; kk += 8) {
      ushort v[8];
#pragma unroll
      for (int j = 0; j < 8; j++) v[j] = f2bf(src[(size_t)(k0 + kk + j) * HD]);
      uint4 pk;
      pk.x = (uint)v[0] | ((uint)v[1] << 16);
      pk.y = (uint)v[2] | ((uint)v[3] << 16);
      pk.z = (uint)v[4] | ((uint)v[5] << 16);
      pk.w = (uint)v[6] | ((uint)v[7] << 16);
      *(uint4*)&dst[kk] = pk;
    }
    return;
  }
  int row = blockIdx.x * 4 + (t >> 6);
  int lane = t & 63;
  const float4* tr = (const float4*)(tmat + (size_t)row * N);
  const float4* ar = (const float4*)(adj + (size_t)row * N);
  float mx = 0.f, s = 0.f;
#pragma unroll
  for (int it = 0; it < 12; it++) {
    float4 t4 = tr[lane + it * 64];
    float4 a4 = ar[lane + it * 64];
    mx = fmaxf(mx, fmaxf(fmaxf(t4.x, t4.y), fmaxf(t4.z, t4.w)));
    s += a4.x + a4.y + a4.z + a4.w;
  }
  for (int o = 32; o > 0; o >>= 1) { mx = fmaxf(mx, __shfl_xor(mx, o)); s += __shfl_xor(s, o); }
  __shared__ float smx[4];
  int w = t >> 6;
  if (lane == 0) { deg0[row] = (s == 0.f) ? 1u : 0u; smx[w] = mx; }
  __syncthreads();
  if (t == 0) {
    float m = fmaxf(fmaxf(smx[0], smx[1]), fmaxf(smx[2], smx[3]));
    atomicMax(tmax_u, __float_as_uint(m));
  }
}

// ---- fused x-build + MFMA h-GEMM + es/ed + hT. 16 rows/block, 192 blocks.
// layer0: x = emb@Ws+bs (Ws staged f32 in LDS). layer1: x = LN(ELU(o/s)).
// h via mfma_16x16x32_bf16: A = x-tile, B = WT (pre-transposed). es/ed from f32 accs.
__global__ __launch_bounds__(256) void k_hx(int layer,
                                            const float* __restrict__ emb,
                                            const float* __restrict__ Ws,
                                            const float* __restrict__ bs,
                                            const float* __restrict__ o_part,
                                            const float* __restrict__ s_part,
                                            const float* __restrict__ lg,
                                            const float* __restrict__ lb,
                                            const ushort* __restrict__ wt,
                                            const float* __restrict__ gA,
                                            ushort* __restrict__ hT,
                                            float* __restrict__ es,
                                            float* __restrict__ ed) {
  __shared__ __align__(16) ushort wlds[HID][136];   // 34816 B (also reused as f32 Ws buf)
  __shared__ __align__(16) ushort xs2[16][17][8];   // 4352 B  x in A-frag subtile layout
  __shared__ __align__(16) float embs[16][D_IN];    // 4096 B
  int t = threadIdx.x;
  int n0 = blockIdx.x * 16;
  int r = t >> 4, q = t & 15, c0 = q * 8;

  if (layer == 0) {
    // stage Ws (f32, 8192 floats) into wlds region + embs
    float* wsf = (float*)&wlds[0][0];
    const float4* Ws4 = (const float4*)Ws;
    float4* wsf4 = (float4*)wsf;
#pragma unroll
    for (int j = 0; j < 8; j++) wsf4[t + j * 256] = Ws4[t + j * 256];
    ((float4*)&embs[0][0])[t] = ((const float4*)(emb + (size_t)n0 * D_IN))[t];
    __syncthreads();
    // x-build: row r, cols c0..c0+7
    float acc[8];
    float4 b0 = *(const float4*)&bs[c0];
    float4 b1 = *(const float4*)&bs[c0 + 4];
    acc[0] = b0.x; acc[1] = b0.y; acc[2] = b0.z; acc[3] = b0.w;
    acc[4] = b1.x; acc[5] = b1.y; acc[6] = b1.z; acc[7] = b1.w;
    for (int i = 0; i < D_IN; i++) {
      float ev = embs[r][i];
      float4 w0 = *(const float4*)&wsf[i * HID + c0];
      float4 w1 = *(const float4*)&wsf[i * HID + c0 + 4];
      acc[0] += ev * w0.x; acc[1] += ev * w0.y; acc[2] += ev * w0.z; acc[3] += ev * w0.w;
      acc[4] += ev * w1.x; acc[5] += ev * w1.y; acc[6] += ev * w1.z; acc[7] += ev * w1.w;
    }
    uint4 pk;
    pk.x = (uint)f2bf(acc[0]) | ((uint)f2bf(acc[1]) << 16);
    pk.y = (uint)f2bf(acc[2]) | ((uint)f2bf(acc[3]) << 16);
    pk.z = (uint)f2bf(acc[4]) | ((uint)f2bf(acc[5]) << 16);
    pk.w = (uint)f2bf(acc[6]) | ((uint)f2bf(acc[7]) << 16);
    __syncthreads();   // all Ws reads done before overwrite
    *(uint4*)&xs2[q][r][0] = pk;
    // stage WT bf16 (2048 uint4) into wlds (padded rows)
    const uint4* wt4 = (const uint4*)wt;
#pragma unroll
    for (int j = 0; j < 8; j++) {
      int ci = t + j * 256;
      *(uint4*)&wlds[ci >> 4][(ci & 15) * 8] = wt4[ci];
    }
    __syncthreads();
  } else {
    // stage WT first (loads issue early), combine overlaps
    const uint4* wt4 = (const uint4*)wt;
#pragma unroll
    for (int j = 0; j < 8; j++) {
      int ci = t + j * 256;
      *(uint4*)&wlds[ci >> 4][(ci & 15) * 8] = wt4[ci];
    }
    int i = n0 + r;
    float ox[8] = {0.f, 0.f, 0.f, 0.f, 0.f, 0.f, 0.f, 0.f};
    float sden = 0.f;
#pragma unroll
    for (int sp = 0; sp < TSPLIT; sp++) {
      const float* op = o_part + ((size_t)sp * N + i) * HID + c0;
      float4 a = *(const float4*)op;
      float4 b = *(const float4*)(op + 4);
      ox[0] += a.x; ox[1] += a.y; ox[2] += a.z; ox[3] += a.w;
      ox[4] += b.x; ox[5] += b.y; ox[6] += b.z; ox[7] += b.w;
      sden += s_part[((size_t)sp * N + i) * NH + (c0 >> 5)];
    }
    float v[8], sm = 0.f, sq = 0.f;
#pragma unroll
    for (int j = 0; j < 8; j++) {
      float x = ox[j] / sden;
      x = x > 0.f ? x : expm1f(x);
      v[j] = x; sm += x; sq += x * x;
    }
    sm += __shfl_xor(sm, 1); sq += __shfl_xor(sq, 1);
    sm += __shfl_xor(sm, 2); sq += __shfl_xor(sq, 2);
    sm += __shfl_xor(sm, 4); sq += __shfl_xor(sq, 4);
    sm += __shfl_xor(sm, 8); sq += __shfl_xor(sq, 8);
    float mu = sm / (float)HID;
    float var = sq / (float)HID - mu * mu;
    float rs = rsqrtf(var + EPS);
    float4 g0 = *(const float4*)&lg[c0], g1 = *(const float4*)&lg[c0 + 4];
    float4 bb0 = *(const float4*)&lb[c0], bb1 = *(const float4*)&lb[c0 + 4];
    float xo[8];
    xo[0] = (v[0] - mu) * rs * g0.x + bb0.x; xo[1] = (v[1] - mu) * rs * g0.y + bb0.y;
    xo[2] = (v[2] - mu) * rs * g0.z + bb0.z; xo[3] = (v[3] - mu) * rs * g0.w + bb0.w;
    xo[4] = (v[4] - mu) * rs * g1.x + bb1.x; xo[5] = (v[5] - mu) * rs * g1.y + bb1.y;
    xo[6] = (v[6] - mu) * rs * g1.z + bb1.z; xo[7] = (v[7] - mu) * rs * g1.w + bb1.w;
    uint4 pk;
    pk.x = (uint)f2bf(xo[0]) | ((uint)f2bf(xo[1]) << 16);
    pk.y = (uint)f2bf(xo[2]) | ((uint)f2bf(xo[3]) << 16);
    pk.z = (uint)f2bf(xo[4]) | ((uint)f2bf(xo[5]) << 16);
    pk.w = (uint)f2bf(xo[6]) | ((uint)f2bf(xo[7]) << 16);
    *(uint4*)&xs2[q][r][0] = pk;
    __syncthreads();
  }

  // ---- MFMA: wave w = head w. A row m=l&15, k=(l>>4)*8+e; B col=l&15 (n), same k; C col=l&15,row=(l>>4)*4+reg.
  int w = t >> 6, l = t & 63;
  int m = l & 15, g = l >> 4;
  f32x4 ac0 = {0.f, 0.f, 0.f, 0.f}, ac1 = {0.f, 0.f, 0.f, 0.f};
#pragma unroll
  for (int k0 = 0; k0 < 4; k0++) {
    bf16x8 afr = *(const bf16x8*)&xs2[k0 * 4 + g][m][0];
    bf16x8 bf0 = *(const bf16x8*)&wlds[w * 32 + m][k0 * 32 + g * 8];
    bf16x8 bf1 = *(const bf16x8*)&wlds[w * 32 + 16 + m][k0 * 32 + g * 8];
    ac0 = __builtin_amdgcn_mfma_f32_16x16x32_bf16(afr, bf0, ac0, 0, 0, 0);
    ac1 = __builtin_amdgcn_mfma_f32_16x16x32_bf16(afr, bf1, ac1, 0, 0, 0);
  }
  // es/ed: head w cols; reduce over 16 col-lanes
  const float* aB = gA + w * 2 * HD;
  float as0 = aB[m], as1 = aB[16 + m];
  float ad0 = aB[HD + m], ad1 = aB[HD + 16 + m];
  float esv[4], edv[4];
#pragma unroll
  for (int qq = 0; qq < 4; qq++) {
    float h0 = ac0[qq], h1 = ac1[qq];
    float e_s = h0 * as0 + h1 * as1;
    float e_d = h0 * ad0 + h1 * ad1;
    e_s += __shfl_xor(e_s, 1); e_d += __shfl_xor(e_d, 1);
    e_s += __shfl_xor(e_s, 2); e_d += __shfl_xor(e_d, 2);
    e_s += __shfl_xor(e_s, 4); e_d += __shfl_xor(e_d, 4);
    e_s += __shfl_xor(e_s, 8); e_d += __shfl_xor(e_d, 8);
    esv[qq] = e_s; edv[qq] = e_d;
  }
  if (m == 0) {
    *(float4*)&es[(size_t)w * N + n0 + g * 4] = make_float4(esv[0], esv[1], esv[2], esv[3]);
    *(float4*)&ed[(size_t)w * N + n0 + g * 4] = make_float4(edv[0], edv[1], edv[2], edv[3]);
  }
  // hT (bf16, col-major [col][n]) from accs: 4 consecutive n per lane per subtile
  {
    uint2 p0, p1;
    p0.x = (uint)f2bf(ac0[0]) | ((uint)f2bf(ac0[1]) << 16);
    p0.y = (uint)f2bf(ac0[2]) | ((uint)f2bf(ac0[3]) << 16);
    p1.x = (uint)f2bf(ac1[0]) | ((uint)f2bf(ac1[1]) << 16);
    p1.y = (uint)f2bf(ac1[2]) | ((uint)f2bf(ac1[3]) << 16);
    *(uint2*)&hT[(size_t)(w * 32 + m) * N + n0 + g * 4] = p0;
    *(uint2*)&hT[(size_t)(w * 32 + 16 + m) * N + n0 + g * 4] = p1;
  }
}

// ---- fused score + PV: direct tmat/adj reads, 32 rows/block, dbuf (unchanged) ----
__global__ __launch_bounds__(256) void k_att(const float* __restrict__ tmat,
                                             const float* __restrict__ adj,
                                             const uint* __restrict__ tmax_u,
                                             const ushort* __restrict__ hT,
                                             const float* __restrict__ es,
                                             const float* __restrict__ ed,
                                             const uint* __restrict__ deg0,
                                             float* __restrict__ o_part,
                                             float* __restrict__ s_part) {
  __shared__ __align__(16) ushort ps[2][NH][32][PSTR];
  int tid = threadIdx.x;
  int ib = blockIdx.x * 32;
  int sp = blockIdx.y;
  int jb0 = sp * JSPAN;
  float tmax = __uint_as_float(*tmax_u);
  const float c1 = TD * LOG2E;

  int jl = tid & 31;
  int ig = tid >> 5;
  float esr[4][NH];
  uint dg[4];
#pragma unroll
  for (int p = 0; p < 4; p++) {
    int i = ib + ig + 8 * p;
    dg[p] = deg0[i];
#pragma unroll
    for (int h_ = 0; h_ < NH; h_++) esr[p][h_] = es[h_ * N + i];
  }

  int wv = tid >> 6;
  int ln = tid & 63;
  f32x4 acc00 = {0.f, 0.f, 0.f, 0.f}, acc01 = {0.f, 0.f, 0.f, 0.f};
  f32x4 acc10 = {0.f, 0.f, 0.f, 0.f}, acc11 = {0.f, 0.f, 0.f, 0.f};
  float sacc[4][NH];
#pragma unroll
  for (int p = 0; p < 4; p++)
#pragma unroll
    for (int h_ = 0; h_ < NH; h_++) sacc[p][h_] = 0.f;

  float2 t2v[4], a2v[4], edv[NH];

  auto LOADS = [&](int ch) {
    int j0 = jb0 + ch * 64 + 2 * jl;
#pragma unroll
    for (int p = 0; p < 4; p++) {
      t2v[p] = *(const float2*)&tmat[(size_t)(ib + ig + 8 * p) * N + j0];
      a2v[p] = *(const float2*)&adj[(size_t)(ib + ig + 8 * p) * N + j0];
    }
#pragma unroll
    for (int h_ = 0; h_ < NH; h_++) edv[h_] = *(const float2*)&ed[h_ * N + j0];
  };
  auto COMPUTE = [&](int buf) {
#pragma unroll
    for (int p = 0; p < 4; p++) {
      float m0 = __builtin_amdgcn_exp2f(c1 * (t2v[p].x - tmax)) * LOG2E;
      float m1 = __builtin_amdgcn_exp2f(c1 * (t2v[p].y - tmax)) * LOG2E;
      bool z0 = (a2v[p].x != 0.f), z1 = (a2v[p].y != 0.f);
#pragma unroll
      for (int h_ = 0; h_ < NH; h_++) {
        float e0 = esr[p][h_] + edv[h_].x;
        float e1 = esr[p][h_] + edv[h_].y;
        float l0 = fmaxf(e0, 0.f) + ALPHA * fminf(e0, 0.f);
        float l1 = fmaxf(e1, 0.f) + ALPHA * fminf(e1, 0.f);
        float p0 = __builtin_amdgcn_exp2f(l0 * m0);
        float p1 = __builtin_amdgcn_exp2f(l1 * m1);
        p0 = z0 ? p0 : 0.f;
        p1 = z1 ? p1 : 0.f;
        if (dg[p]) { p0 = 1.f; p1 = 1.f; }
        sacc[p][h_] += p0 + p1;
        uint pk = (__float_as_uint(p0) >> 16) | (__float_as_uint(p1) & 0xFFFF0000u);
        *(uint*)&ps[buf][h_][ig + 8 * p][2 * jl] = pk;
      }
    }
  };

  LOADS(0);
  COMPUTE(0);

  int r = ln & 15, g = ln >> 4;
  for (int ch = 0; ch < NCH; ch++) {
    __syncthreads();
    if (ch + 1 < NCH) LOADS(ch + 1);
    {
      int jb = jb0 + ch * 64;
      const ushort* hTb = hT + (size_t)(wv * HD) * N + jb;
      int buf = ch & 1;
#pragma unroll
      for (int ks = 0; ks < 2; ks++) {
        bf16x8 a0f = *(const bf16x8*)&ps[buf][wv][r][ks * 32 + g * 8];
        bf16x8 a1f = *(const bf16x8*)&ps[buf][wv][16 + r][ks * 32 + g * 8];
        bf16x8 b0 = *(const bf16x8*)(hTb + (size_t)r * N + ks * 32 + g * 8);
        bf16x8 b1 = *(const bf16x8*)(hTb + (size_t)(16 + r) * N + ks * 32 + g * 8);
        acc00 = __builtin_amdgcn_mfma_f32_16x16x32_bf16(a0f, b0, acc00, 0, 0, 0);
        acc01 = __builtin_amdgcn_mfma_f32_16x16x32_bf16(a0f, b1, acc01, 0, 0, 0);
        acc10 = __builtin_amdgcn_mfma_f32_16x16x32_bf16(a1f, b0, acc10, 0, 0, 0);
        acc11 = __builtin_amdgcn_mfma_f32_16x16x32_bf16(a1f, b1, acc11, 0, 0, 0);
      }
    }
    if (ch + 1 < NCH) COMPUTE((ch + 1) & 1);
  }

#pragma unroll
  for (int p = 0; p < 4; p++)
#pragma unroll
    for (int h_ = 0; h_ < NH; h_++) {
      float v = sacc[p][h_];
      v += __shfl_xor(v, 16); v += __shfl_xor(v, 8);
      v += __shfl_xor(v, 4);  v += __shfl_xor(v, 2); v += __shfl_xor(v, 1);
      if (jl == 0) {
        int i = ib + ig + 8 * p;
        s_part[((size_t)sp * N + i) * NH + h_] = v;
      }
    }
  {
#pragma unroll
    for (int qq = 0; qq < 4; qq++) {
      int i0 = ib + g * 4 + qq;
      int i1 = ib + 16 + g * 4 + qq;
      float* op0 = o_part + ((size_t)sp * N + i0) * HID + wv * HD;
      float* op1 = o_part + ((size_t)sp * N + i1) * HID + wv * HD;
      op0[r] = acc00[qq];
      op0[16 + r] = acc01[qq];
      op1[r] = acc10[qq];
      op1[16 + r] = acc11[qq];
    }
  }
}

// ---- final: combine(layer1) for 16 gathered rows + MLP, W1 staged bf16 in LDS ----
__global__ __launch_bounds__(256) void k_final(const float* __restrict__ o_part,
                                               const float* __restrict__ s_part,
                                               const float* __restrict__ lg,
                                               const float* __restrict__ lb,
                                               const int* __restrict__ tid,
                                               const float* __restrict__ attr,
                                               const float* __restrict__ Wa,
                                               const float* __restrict__ ba,
                                               const float* __restrict__ W1,
                                               const float* __restrict__ b1,
                                               const float* __restrict__ W2,
                                               const float* __restrict__ b2,
                                               float* __restrict__ out) {
  __shared__ __align__(16) float tf[16][HID];      // 8 KB
  __shared__ __align__(16) ushort w1lds[HID * HID]; // 32 KB bf16
  int t = threadIdx.x;
  int r = t >> 4, q = t & 15, c0 = q * 8;
  int bI0 = blockIdx.x * 16;
  int id = tid[bI0 + r];
  float av = attr[bI0 + r];
  // stage W1 -> bf16 LDS (2048 uint4 chunks)
  const float4* W14 = (const float4*)W1;
#pragma unroll
  for (int j = 0; j < 8; j++) {
    int ci = t + j * 256;
    float4 a = W14[ci * 2], b = W14[ci * 2 + 1];
    uint4 pk;
    pk.x = (uint)f2bf(a.x) | ((uint)f2bf(a.y) << 16);
    pk.y = (uint)f2bf(a.z) | ((uint)f2bf(a.w) << 16);
    pk.z = (uint)f2bf(b.x) | ((uint)f2bf(b.y) << 16);
    pk.w = (uint)f2bf(b.z) | ((uint)f2bf(b.w) << 16);
    *(uint4*)&w1lds[ci * 8] = pk;
  }
  // combine for row id
  float ox[8] = {0.f, 0.f, 0.f, 0.f, 0.f, 0.f, 0.f, 0.f};
  float sden = 0.f;
#pragma unroll
  for (int sp = 0; sp < TSPLIT; sp++) {
    const float* op = o_part + ((size_t)sp * N + id) * HID + c0;
    float4 a = *(const float4*)op;
    float4 b = *(const float4*)(op + 4);
    ox[0] += a.x; ox[1] += a.y; ox[2] += a.z; ox[3] += a.w;
    ox[4] += b.x; ox[5] += b.y; ox[6] += b.z; ox[7] += b.w;
    sden += s_part[((size_t)sp * N + id) * NH + (c0 >> 5)];
  }
  float v[8], sm = 0.f, sq = 0.f;
#pragma unroll
  for (int j = 0; j < 8; j++) {
    float x = ox[j] / sden;
    x = x > 0.f ? x : expm1f(x);
    v[j] = x; sm += x; sq += x * x;
  }
  sm += __shfl_xor(sm, 1); sq += __shfl_xor(sq, 1);
  sm += __shfl_xor(sm, 2); sq += __shfl_xor(sq, 2);
  sm += __shfl_xor(sm, 4); sq += __shfl_xor(sq, 4);
  sm += __shfl_xor(sm, 8); sq += __shfl_xor(sq, 8);
  float mu = sm / (float)HID;
  float var = sq / (float)HID - mu * mu;
  float rs = rsqrtf(var + EPS);
#pragma unroll
  for (int j = 0; j < 8; j++) {
    int c = c0 + j;
    tf[r][c] = (v[j] - mu) * rs * lg[c] + lb[c] + av * Wa[c] + ba[c];
  }
  __syncthreads();
  // MLP: hid[c0..c0+7] for row r
  float hid[8];
  float4 bb0 = *(const float4*)&b1[c0], bb1 = *(const float4*)&b1[c0 + 4];
  hid[0] = bb0.x; hid[1] = bb0.y; hid[2] = bb0.z; hid[3] = bb0.w;
  hid[4] = bb1.x; hid[5] = bb1.y; hid[6] = bb1.z; hid[7] = bb1.w;
  for (int i = 0; i < HID; i++) {
    float tv = tf[r][i];
    uint4 wv = *(const uint4*)&w1lds[i * HID + c0];
    hid[0] += tv * bf2f((ushort)(wv.x & 0xFFFFu));
    hid[1] += tv * bf2f((ushort)(wv.x >> 16));
    hid[2] += tv * bf2f((ushort)(wv.y & 0xFFFFu));
    hid[3] += tv * bf2f((ushort)(wv.y >> 16));
    hid[4] += tv * bf2f((ushort)(wv.z & 0xFFFFu));
    hid[5] += tv * bf2f((ushort)(wv.z >> 16));
    hid[6] += tv * bf2f((ushort)(wv.w & 0xFFFFu));
    hid[7] += tv * bf2f((ushort)(wv.w >> 16));
  }
  float pr = 0.f;
#pragma unroll
  for (int j = 0; j < 8; j++) pr += fmaxf(hid[j], 0.f) * W2[c0 + j];
  pr += __shfl_xor(pr, 1);
  pr += __shfl_xor(pr, 2);
  pr += __shfl_xor(pr, 4);
  pr += __shfl_xor(pr, 8);
  if (q == 0) out[bI0 + r] = pr + b2[0];
}

extern "C" void kernel_launch(void* const* d_in, const int* in_sizes, int n_in,
                              void* d_out, int out_size, void* d_ws, size_t ws_size,
                              hipStream_t stream) {
  (void)in_sizes; (void)n_in; (void)out_size; (void)ws_size;
  const int*   topic_ids = (const int*)d_in[0];
  const float* adj  = (const float*)d_in[1];
  const float* tmat = (const float*)d_in[2];
  const float* attr = (const float*)d_in[3];
  const float* emb  = (const float*)d_in[4];
  const float* Ws   = (const float*)d_in[5];
  const float* bs   = (const float*)d_in[6];
  const float* Wa   = (const float*)d_in[7];
  const float* ba   = (const float*)d_in[8];
  const float* gW   = (const float*)d_in[9];
  const float* gA   = (const float*)d_in[10];
  const float* lng  = (const float*)d_in[11];
  const float* lnb  = (const float*)d_in[12];
  const float* W1   = (const float*)d_in[13];
  const float* b1   = (const float*)d_in[14];
  const float* W2   = (const float*)d_in[15];
  const float* b2   = (const float*)d_in[16];

  char* ws = (char*)d_ws;
  size_t o = 0;
  auto alloc = [&](size_t bytes) { void* p = ws + o; o += (bytes + 255) & ~255ull; return p; };
  uint*   tmax_u = (uint*)alloc(4);
  uint*   deg0   = (uint*)alloc((size_t)N * 4);
  ushort* hT     = (ushort*)alloc((size_t)HID * N * 2);
  float*  es     = (float*)alloc((size_t)NH * N * 4);
  float*  ed     = (float*)alloc((size_t)NH * N * 4);
  float*  o_part = (float*)alloc((size_t)TSPLIT * N * HID * 4);
  float*  s_part = (float*)alloc((size_t)TSPLIT * N * NH * 4);
  ushort* wt     = (ushort*)alloc((size_t)2 * HID * HID * 2);

  hipMemsetAsync(tmax_u, 0, 4, stream);
  k_prep<<<N / 4 + 2, 256, 0, stream>>>(tmat, adj, gW, tmax_u, deg0, wt);

  dim3 gr(N / 32, TSPLIT);
  // layer 0
  k_hx<<<N / 16, 256, 0, stream>>>(0, emb, Ws, bs, nullptr, nullptr, nullptr, nullptr,
                                   wt, gA, hT, es, ed);
  k_att<<<gr, 256, 0, stream>>>(tmat, adj, tmax_u, hT, es, ed, deg0, o_part, s_part);
  // layer 1 (combine of layer 0 fused in)
  k_hx<<<N / 16, 256, 0, stream>>>(1, nullptr, nullptr, nullptr, o_part, s_part, lng, lnb,
                                   wt + (size_t)HID * HID, gA + (size_t)NH * 2 * HD,
                                   hT, es, ed);
  k_att<<<gr, 256, 0, stream>>>(tmat, adj, tmax_u, hT, es, ed, deg0, o_part, s_part);
  // final (combine of layer 1 fused in)
  k_final<<<NB / 16, 256, 0, stream>>>(o_part, s_part, lng + HID, lnb + HID,
                                       topic_ids, attr, Wa, ba, W1, b1, W2, b2, (float*)d_out);
}

// Round 12
// 200.529 us; speedup vs baseline: 1.3232x; 1.0989x over previous
//
#include <hip/hip_runtime.h>

#define N 3072
#define D_IN 64
#define HID 128
#define NH 4
#define HD 32
#define NB 1024
#define ALPHA 0.2f
#define TD 0.1f
#define EPS 1e-5f
#define LOG2E 1.4426950408889634f
#define TSPLIT 8
#define JSPAN (N / TSPLIT)  /* 384 */
#define NCH (JSPAN / 64)    /* 6   */
#define PSTR 72             /* padded bf16 row stride for p tiles */

typedef unsigned int uint;
typedef unsigned short ushort;
typedef __attribute__((ext_vector_type(8))) __bf16 bf16x8;
typedef __attribute__((ext_vector_type(4))) float f32x4;

__device__ __forceinline__ ushort f2bf(float f) {
  union { float f; uint u; } c; c.f = f;
  uint u = c.u;
  return (ushort)((u + 0x7FFFu + ((u >> 16) & 1u)) >> 16);
}
__device__ __forceinline__ float bf2f(ushort u) {
  union { uint u; float f; } c; c.u = ((uint)u) << 16;
  return c.f;
}

// ---- self-transpose helper: gWl (f32 [h][k][o]) -> wlds[n=h*32+o][k] bf16 ----
__device__ __forceinline__ void stage_wt(const float* __restrict__ gWl,
                                         ushort (*wlds)[136], int t) {
  const float4* g4 = (const float4*)gWl;
#pragma unroll
  for (int j = 0; j < 16; j++) {
    int f = t + j * 256;
    float4 v = g4[f];
    int h = f >> 10, kk = (f >> 3) & 127, o4 = (f & 7) * 4;
    ushort* base = &wlds[(h << 5) + o4][kk];
    base[0] = f2bf(v.x);
    base[136] = f2bf(v.y);
    base[272] = f2bf(v.z);
    base[408] = f2bf(v.w);
  }
}

// ---- MFMA h-GEMM tail shared by both hx kernels ----
__device__ __forceinline__ void hx_tail(const ushort (*wlds)[136],
                                        const ushort (*xs2)[17][8],
                                        const float* __restrict__ gA,
                                        ushort* __restrict__ hT,
                                        float* __restrict__ es,
                                        float* __restrict__ ed,
                                        int n0, int t) {
  int w = t >> 6, l = t & 63;
  int m = l & 15, g = l >> 4;
  f32x4 ac0 = {0.f, 0.f, 0.f, 0.f}, ac1 = {0.f, 0.f, 0.f, 0.f};
#pragma unroll
  for (int k0 = 0; k0 < 4; k0++) {
    bf16x8 afr = *(const bf16x8*)&xs2[k0 * 4 + g][m][0];
    bf16x8 bf0 = *(const bf16x8*)&wlds[w * 32 + m][k0 * 32 + g * 8];
    bf16x8 bf1 = *(const bf16x8*)&wlds[w * 32 + 16 + m][k0 * 32 + g * 8];
    ac0 = __builtin_amdgcn_mfma_f32_16x16x32_bf16(afr, bf0, ac0, 0, 0, 0);
    ac1 = __builtin_amdgcn_mfma_f32_16x16x32_bf16(afr, bf1, ac1, 0, 0, 0);
  }
  const float* aB = gA + w * 2 * HD;
  float as0 = aB[m], as1 = aB[16 + m];
  float ad0 = aB[HD + m], ad1 = aB[HD + 16 + m];
  float esv[4], edv[4];
#pragma unroll
  for (int qq = 0; qq < 4; qq++) {
    float h0 = ac0[qq], h1 = ac1[qq];
    float e_s = h0 * as0 + h1 * as1;
    float e_d = h0 * ad0 + h1 * ad1;
    e_s += __shfl_xor(e_s, 1); e_d += __shfl_xor(e_d, 1);
    e_s += __shfl_xor(e_s, 2); e_d += __shfl_xor(e_d, 2);
    e_s += __shfl_xor(e_s, 4); e_d += __shfl_xor(e_d, 4);
    e_s += __shfl_xor(e_s, 8); e_d += __shfl_xor(e_d, 8);
    esv[qq] = e_s; edv[qq] = e_d;
  }
  if (m == 0) {
    *(float4*)&es[(size_t)w * N + n0 + g * 4] = make_float4(esv[0], esv[1], esv[2], esv[3]);
    *(float4*)&ed[(size_t)w * N + n0 + g * 4] = make_float4(edv[0], edv[1], edv[2], edv[3]);
  }
  uint2 p0, p1;
  p0.x = (uint)f2bf(ac0[0]) | ((uint)f2bf(ac0[1]) << 16);
  p0.y = (uint)f2bf(ac0[2]) | ((uint)f2bf(ac0[3]) << 16);
  p1.x = (uint)f2bf(ac1[0]) | ((uint)f2bf(ac1[1]) << 16);
  p1.y = (uint)f2bf(ac1[2]) | ((uint)f2bf(ac1[3]) << 16);
  *(uint2*)&hT[(size_t)(w * 32 + m) * N + n0 + g * 4] = p0;
  *(uint2*)&hT[(size_t)(w * 32 + 16 + m) * N + n0 + g * 4] = p1;
}

// ---- node A: blocks 0-191 = hx layer0 (emb@Ws+bs -> h); blocks 192-959 = prep rows ----
__global__ __launch_bounds__(256) void k_hx0p(const float* __restrict__ tmat,
                                              const float* __restrict__ adj,
                                              const float* __restrict__ emb,
                                              const float* __restrict__ Ws,
                                              const float* __restrict__ bs,
                                              const float* __restrict__ gW,
                                              const float* __restrict__ gA,
                                              ushort* __restrict__ hT,
                                              float* __restrict__ es,
                                              float* __restrict__ ed,
                                              float* __restrict__ rowmax,
                                              uint* __restrict__ deg0) {
  int t = threadIdx.x;
  if (blockIdx.x >= N / 16) {
    // ---- prep branch: 4 rows/block ----
    int row = (blockIdx.x - N / 16) * 4 + (t >> 6);
    int lane = t & 63;
    const float4* tr = (const float4*)(tmat + (size_t)row * N);
    const float4* ar = (const float4*)(adj + (size_t)row * N);
    float mx = 0.f, s = 0.f;
#pragma unroll
    for (int it = 0; it < 12; it++) {
      float4 t4 = tr[lane + it * 64];
      float4 a4 = ar[lane + it * 64];
      mx = fmaxf(mx, fmaxf(fmaxf(t4.x, t4.y), fmaxf(t4.z, t4.w)));
      s += a4.x + a4.y + a4.z + a4.w;
    }
    for (int o = 32; o > 0; o >>= 1) { mx = fmaxf(mx, __shfl_xor(mx, o)); s += __shfl_xor(s, o); }
    if (lane == 0) { rowmax[row] = mx; deg0[row] = (s == 0.f) ? 1u : 0u; }
    return;
  }
  // ---- hx0 branch ----
  __shared__ __align__(16) ushort wlds[HID][136];
  __shared__ __align__(16) ushort xs2[16][17][8];
  __shared__ __align__(16) float embs[16][D_IN];
  int n0 = blockIdx.x * 16;
  int r = t >> 4, q = t & 15, c0 = q * 8;

  float* wsf = (float*)&wlds[0][0];
  const float4* Ws4 = (const float4*)Ws;
  float4* wsf4 = (float4*)wsf;
#pragma unroll
  for (int j = 0; j < 8; j++) wsf4[t + j * 256] = Ws4[t + j * 256];
  ((float4*)&embs[0][0])[t] = ((const float4*)(emb + (size_t)n0 * D_IN))[t];
  __syncthreads();
  float acc[8];
  float4 b0 = *(const float4*)&bs[c0];
  float4 b1 = *(const float4*)&bs[c0 + 4];
  acc[0] = b0.x; acc[1] = b0.y; acc[2] = b0.z; acc[3] = b0.w;
  acc[4] = b1.x; acc[5] = b1.y; acc[6] = b1.z; acc[7] = b1.w;
  for (int i = 0; i < D_IN; i++) {
    float ev = embs[r][i];
    float4 w0 = *(const float4*)&wsf[i * HID + c0];
    float4 w1 = *(const float4*)&wsf[i * HID + c0 + 4];
    acc[0] += ev * w0.x; acc[1] += ev * w0.y; acc[2] += ev * w0.z; acc[3] += ev * w0.w;
    acc[4] += ev * w1.x; acc[5] += ev * w1.y; acc[6] += ev * w1.z; acc[7] += ev * w1.w;
  }
  uint4 pk;
  pk.x = (uint)f2bf(acc[0]) | ((uint)f2bf(acc[1]) << 16);
  pk.y = (uint)f2bf(acc[2]) | ((uint)f2bf(acc[3]) << 16);
  pk.z = (uint)f2bf(acc[4]) | ((uint)f2bf(acc[5]) << 16);
  pk.w = (uint)f2bf(acc[6]) | ((uint)f2bf(acc[7]) << 16);
  __syncthreads();               // all Ws reads complete before wlds overwrite
  *(uint4*)&xs2[q][r][0] = pk;
  stage_wt(gW, wlds, t);         // layer-0 weights -> WT bf16
  __syncthreads();
  hx_tail(wlds, xs2, gA, hT, es, ed, n0, t);
}

// ---- node C: hx layer1 = combine(layer0 partials) -> LN -> h ----
__global__ __launch_bounds__(256) void k_hx1(const float* __restrict__ o_part,
                                             const float* __restrict__ s_part,
                                             const float* __restrict__ lg,
                                             const float* __restrict__ lb,
                                             const float* __restrict__ gW1,
                                             const float* __restrict__ gA,
                                             ushort* __restrict__ hT,
                                             float* __restrict__ es,
                                             float* __restrict__ ed) {
  __shared__ __align__(16) ushort wlds[HID][136];
  __shared__ __align__(16) ushort xs2[16][17][8];
  int t = threadIdx.x;
  int n0 = blockIdx.x * 16;
  int r = t >> 4, q = t & 15, c0 = q * 8;

  stage_wt(gW1, wlds, t);        // issue weight loads early
  int i = n0 + r;
  float ox[8] = {0.f, 0.f, 0.f, 0.f, 0.f, 0.f, 0.f, 0.f};
  float sden = 0.f;
#pragma unroll
  for (int sp = 0; sp < TSPLIT; sp++) {
    const float* op = o_part + ((size_t)sp * N + i) * HID + c0;
    float4 a = *(const float4*)op;
    float4 b = *(const float4*)(op + 4);
    ox[0] += a.x; ox[1] += a.y; ox[2] += a.z; ox[3] += a.w;
    ox[4] += b.x; ox[5] += b.y; ox[6] += b.z; ox[7] += b.w;
    sden += s_part[((size_t)sp * N + i) * NH + (c0 >> 5)];
  }
  float v[8], sm = 0.f, sq = 0.f;
#pragma unroll
  for (int j = 0; j < 8; j++) {
    float x = ox[j] / sden;
    x = x > 0.f ? x : expm1f(x);
    v[j] = x; sm += x; sq += x * x;
  }
  sm += __shfl_xor(sm, 1); sq += __shfl_xor(sq, 1);
  sm += __shfl_xor(sm, 2); sq += __shfl_xor(sq, 2);
  sm += __shfl_xor(sm, 4); sq += __shfl_xor(sq, 4);
  sm += __shfl_xor(sm, 8); sq += __shfl_xor(sq, 8);
  float mu = sm / (float)HID;
  float var = sq / (float)HID - mu * mu;
  float rs = rsqrtf(var + EPS);
  float4 g0 = *(const float4*)&lg[c0], g1 = *(const float4*)&lg[c0 + 4];
  float4 bb0 = *(const float4*)&lb[c0], bb1 = *(const float4*)&lb[c0 + 4];
  float xo[8];
  xo[0] = (v[0] - mu) * rs * g0.x + bb0.x; xo[1] = (v[1] - mu) * rs * g0.y + bb0.y;
  xo[2] = (v[2] - mu) * rs * g0.z + bb0.z; xo[3] = (v[3] - mu) * rs * g0.w + bb0.w;
  xo[4] = (v[4] - mu) * rs * g1.x + bb1.x; xo[5] = (v[5] - mu) * rs * g1.y + bb1.y;
  xo[6] = (v[6] - mu) * rs * g1.z + bb1.z; xo[7] = (v[7] - mu) * rs * g1.w + bb1.w;
  uint4 pk;
  pk.x = (uint)f2bf(xo[0]) | ((uint)f2bf(xo[1]) << 16);
  pk.y = (uint)f2bf(xo[2]) | ((uint)f2bf(xo[3]) << 16);
  pk.z = (uint)f2bf(xo[4]) | ((uint)f2bf(xo[5]) << 16);
  pk.w = (uint)f2bf(xo[6]) | ((uint)f2bf(xo[7]) << 16);
  *(uint4*)&xs2[q][r][0] = pk;
  __syncthreads();
  hx_tail(wlds, xs2, gA, hT, es, ed, n0, t);
}

// ---- fused score + PV: 32 rows/block, TSPLIT=8, dbuf; tmax reduced from rowmax ----
__global__ __launch_bounds__(256) void k_att(const float* __restrict__ tmat,
                                             const float* __restrict__ adj,
                                             const float* __restrict__ rowmax,
                                             const ushort* __restrict__ hT,
                                             const float* __restrict__ es,
                                             const float* __restrict__ ed,
                                             const uint* __restrict__ deg0,
                                             float* __restrict__ o_part,
                                             float* __restrict__ s_part) {
  __shared__ __align__(16) ushort ps[2][NH][32][PSTR];
  __shared__ float redl[4];
  int tid = threadIdx.x;
  int ib = blockIdx.x * 32;
  int sp = blockIdx.y;
  int jb0 = sp * JSPAN;
  const float c1 = TD * LOG2E;

  // reduce global tmax from rowmax[3072]
  {
    float m = 0.f;
#pragma unroll
    for (int j = 0; j < 12; j++) m = fmaxf(m, rowmax[tid + j * 256]);
    for (int o = 32; o > 0; o >>= 1) m = fmaxf(m, __shfl_xor(m, o));
    if ((tid & 63) == 0) redl[tid >> 6] = m;
  }
  __syncthreads();
  float tmax = fmaxf(fmaxf(redl[0], redl[1]), fmaxf(redl[2], redl[3]));

  int jl = tid & 31;
  int ig = tid >> 5;
  float esr[4][NH];
  uint dg[4];
#pragma unroll
  for (int p = 0; p < 4; p++) {
    int i = ib + ig + 8 * p;
    dg[p] = deg0[i];
#pragma unroll
    for (int h_ = 0; h_ < NH; h_++) esr[p][h_] = es[h_ * N + i];
  }

  int wv = tid >> 6;
  int ln = tid & 63;
  f32x4 acc00 = {0.f, 0.f, 0.f, 0.f}, acc01 = {0.f, 0.f, 0.f, 0.f};
  f32x4 acc10 = {0.f, 0.f, 0.f, 0.f}, acc11 = {0.f, 0.f, 0.f, 0.f};
  float sacc[4][NH];
#pragma unroll
  for (int p = 0; p < 4; p++)
#pragma unroll
    for (int h_ = 0; h_ < NH; h_++) sacc[p][h_] = 0.f;

  float2 t2v[4], a2v[4], edv[NH];

  auto LOADS = [&](int ch) {
    int j0 = jb0 + ch * 64 + 2 * jl;
#pragma unroll
    for (int p = 0; p < 4; p++) {
      t2v[p] = *(const float2*)&tmat[(size_t)(ib + ig + 8 * p) * N + j0];
      a2v[p] = *(const float2*)&adj[(size_t)(ib + ig + 8 * p) * N + j0];
    }
#pragma unroll
    for (int h_ = 0; h_ < NH; h_++) edv[h_] = *(const float2*)&ed[h_ * N + j0];
  };
  auto COMPUTE = [&](int buf) {
#pragma unroll
    for (int p = 0; p < 4; p++) {
      float m0 = __builtin_amdgcn_exp2f(c1 * (t2v[p].x - tmax)) * LOG2E;
      float m1 = __builtin_amdgcn_exp2f(c1 * (t2v[p].y - tmax)) * LOG2E;
      bool z0 = (a2v[p].x != 0.f), z1 = (a2v[p].y != 0.f);
#pragma unroll
      for (int h_ = 0; h_ < NH; h_++) {
        float e0 = esr[p][h_] + edv[h_].x;
        float e1 = esr[p][h_] + edv[h_].y;
        float l0 = fmaxf(e0, 0.f) + ALPHA * fminf(e0, 0.f);
        float l1 = fmaxf(e1, 0.f) + ALPHA * fminf(e1, 0.f);
        float p0 = __builtin_amdgcn_exp2f(l0 * m0);
        float p1 = __builtin_amdgcn_exp2f(l1 * m1);
        p0 = z0 ? p0 : 0.f;
        p1 = z1 ? p1 : 0.f;
        if (dg[p]) { p0 = 1.f; p1 = 1.f; }
        sacc[p][h_] += p0 + p1;
        uint pk = (__float_as_uint(p0) >> 16) | (__float_as_uint(p1) & 0xFFFF0000u);
        *(uint*)&ps[buf][h_][ig + 8 * p][2 * jl] = pk;
      }
    }
  };

  LOADS(0);
  COMPUTE(0);

  int r = ln & 15, g = ln >> 4;
  for (int ch = 0; ch < NCH; ch++) {
    __syncthreads();
    if (ch + 1 < NCH) LOADS(ch + 1);
    {
      int jb = jb0 + ch * 64;
      const ushort* hTb = hT + (size_t)(wv * HD) * N + jb;
      int buf = ch & 1;
#pragma unroll
      for (int ks = 0; ks < 2; ks++) {
        bf16x8 a0f = *(const bf16x8*)&ps[buf][wv][r][ks * 32 + g * 8];
        bf16x8 a1f = *(const bf16x8*)&ps[buf][wv][16 + r][ks * 32 + g * 8];
        bf16x8 b0 = *(const bf16x8*)(hTb + (size_t)r * N + ks * 32 + g * 8);
        bf16x8 b1 = *(const bf16x8*)(hTb + (size_t)(16 + r) * N + ks * 32 + g * 8);
        acc00 = __builtin_amdgcn_mfma_f32_16x16x32_bf16(a0f, b0, acc00, 0, 0, 0);
        acc01 = __builtin_amdgcn_mfma_f32_16x16x32_bf16(a0f, b1, acc01, 0, 0, 0);
        acc10 = __builtin_amdgcn_mfma_f32_16x16x32_bf16(a1f, b0, acc10, 0, 0, 0);
        acc11 = __builtin_amdgcn_mfma_f32_16x16x32_bf16(a1f, b1, acc11, 0, 0, 0);
      }
    }
    if (ch + 1 < NCH) COMPUTE((ch + 1) & 1);
  }

#pragma unroll
  for (int p = 0; p < 4; p++)
#pragma unroll
    for (int h_ = 0; h_ < NH; h_++) {
      float v = sacc[p][h_];
      v += __shfl_xor(v, 16); v += __shfl_xor(v, 8);
      v += __shfl_xor(v, 4);  v += __shfl_xor(v, 2); v += __shfl_xor(v, 1);
      if (jl == 0) {
        int i = ib + ig + 8 * p;
        s_part[((size_t)sp * N + i) * NH + h_] = v;
      }
    }
  {
#pragma unroll
    for (int qq = 0; qq < 4; qq++) {
      int i0 = ib + g * 4 + qq;
      int i1 = ib + 16 + g * 4 + qq;
      float* op0 = o_part + ((size_t)sp * N + i0) * HID + wv * HD;
      float* op1 = o_part + ((size_t)sp * N + i1) * HID + wv * HD;
      op0[r] = acc00[qq];
      op0[16 + r] = acc01[qq];
      op1[r] = acc10[qq];
      op1[16 + r] = acc11[qq];
    }
  }
}

// ---- final: combine(layer1) for 16 gathered rows + MLP, W1 staged bf16 in LDS ----
__global__ __launch_bounds__(256) void k_final(const float* __restrict__ o_part,
                                               const float* __restrict__ s_part,
                                               const float* __restrict__ lg,
                                               const float* __restrict__ lb,
                                               const int* __restrict__ tid,
                                               const float* __restrict__ attr,
                                               const float* __restrict__ Wa,
                                               const float* __restrict__ ba,
                                               const float* __restrict__ W1,
                                               const float* __restrict__ b1,
                                               const float* __restrict__ W2,
                                               const float* __restrict__ b2,
                                               float* __restrict__ out) {
  __shared__ __align__(16) float tf[16][HID];
  __shared__ __align__(16) ushort w1lds[HID * HID];
  int t = threadIdx.x;
  int r = t >> 4, q = t & 15, c0 = q * 8;
  int bI0 = blockIdx.x * 16;
  int id = tid[bI0 + r];
  float av = attr[bI0 + r];
  const float4* W14 = (const float4*)W1;
#pragma unroll
  for (int j = 0; j < 8; j++) {
    int ci = t + j * 256;
    float4 a = W14[ci * 2], b = W14[ci * 2 + 1];
    uint4 pk;
    pk.x = (uint)f2bf(a.x) | ((uint)f2bf(a.y) << 16);
    pk.y = (uint)f2bf(a.z) | ((uint)f2bf(a.w) << 16);
    pk.z = (uint)f2bf(b.x) | ((uint)f2bf(b.y) << 16);
    pk.w = (uint)f2bf(b.z) | ((uint)f2bf(b.w) << 16);
    *(uint4*)&w1lds[ci * 8] = pk;
  }
  float ox[8] = {0.f, 0.f, 0.f, 0.f, 0.f, 0.f, 0.f, 0.f};
  float sden = 0.f;
#pragma unroll
  for (int sp = 0; sp < TSPLIT; sp++) {
    const float* op = o_part + ((size_t)sp * N + id) * HID + c0;
    float4 a = *(const float4*)op;
    float4 b = *(const float4*)(op + 4);
    ox[0] += a.x; ox[1] += a.y; ox[2] += a.z; ox[3] += a.w;
    ox[4] += b.x; ox[5] += b.y; ox[6] += b.z; ox[7] += b.w;
    sden += s_part[((size_t)sp * N + id) * NH + (c0 >> 5)];
  }
  float v[8], sm = 0.f, sq = 0.f;
#pragma unroll
  for (int j = 0; j < 8; j++) {
    float x = ox[j] / sden;
    x = x > 0.f ? x : expm1f(x);
    v[j] = x; sm += x; sq += x * x;
  }
  sm += __shfl_xor(sm, 1); sq += __shfl_xor(sq, 1);
  sm += __shfl_xor(sm, 2); sq += __shfl_xor(sq, 2);
  sm += __shfl_xor(sm, 4); sq += __shfl_xor(sq, 4);
  sm += __shfl_xor(sm, 8); sq += __shfl_xor(sq, 8);
  float mu = sm / (float)HID;
  float var = sq / (float)HID - mu * mu;
  float rs = rsqrtf(var + EPS);
#pragma unroll
  for (int j = 0; j < 8; j++) {
    int c = c0 + j;
    tf[r][c] = (v[j] - mu) * rs * lg[c] + lb[c] + av * Wa[c] + ba[c];
  }
  __syncthreads();
  float hid[8];
  float4 bb0 = *(const float4*)&b1[c0], bb1 = *(const float4*)&b1[c0 + 4];
  hid[0] = bb0.x; hid[1] = bb0.y; hid[2] = bb0.z; hid[3] = bb0.w;
  hid[4] = bb1.x; hid[5] = bb1.y; hid[6] = bb1.z; hid[7] = bb1.w;
  for (int i = 0; i < HID; i++) {
    float tv = tf[r][i];
    uint4 wv = *(const uint4*)&w1lds[i * HID + c0];
    hid[0] += tv * bf2f((ushort)(wv.x & 0xFFFFu));
    hid[1] += tv * bf2f((ushort)(wv.x >> 16));
    hid[2] += tv * bf2f((ushort)(wv.y & 0xFFFFu));
    hid[3] += tv * bf2f((ushort)(wv.y >> 16));
    hid[4] += tv * bf2f((ushort)(wv.z & 0xFFFFu));
    hid[5] += tv * bf2f((ushort)(wv.z >> 16));
    hid[6] += tv * bf2f((ushort)(wv.w & 0xFFFFu));
    hid[7] += tv * bf2f((ushort)(wv.w >> 16));
  }
  float pr = 0.f;
#pragma unroll
  for (int j = 0; j < 8; j++) pr += fmaxf(hid[j], 0.f) * W2[c0 + j];
  pr += __shfl_xor(pr, 1);
  pr += __shfl_xor(pr, 2);
  pr += __shfl_xor(pr, 4);
  pr += __shfl_xor(pr, 8);
  if (q == 0) out[bI0 + r] = pr + b2[0];
}

extern "C" void kernel_launch(void* const* d_in, const int* in_sizes, int n_in,
                              void* d_out, int out_size, void* d_ws, size_t ws_size,
                              hipStream_t stream) {
  (void)in_sizes; (void)n_in; (void)out_size; (void)ws_size;
  const int*   topic_ids = (const int*)d_in[0];
  const float* adj  = (const float*)d_in[1];
  const float* tmat = (const float*)d_in[2];
  const float* attr = (const float*)d_in[3];
  const float* emb  = (const float*)d_in[4];
  const float* Ws   = (const float*)d_in[5];
  const float* bs   = (const float*)d_in[6];
  const float* Wa   = (const float*)d_in[7];
  const float* ba   = (const float*)d_in[8];
  const float* gW   = (const float*)d_in[9];
  const float* gA   = (const float*)d_in[10];
  const float* lng  = (const float*)d_in[11];
  const float* lnb  = (const float*)d_in[12];
  const float* W1   = (const float*)d_in[13];
  const float* b1   = (const float*)d_in[14];
  const float* W2   = (const float*)d_in[15];
  const float* b2   = (const float*)d_in[16];

  char* ws = (char*)d_ws;
  size_t o = 0;
  auto alloc = [&](size_t bytes) { void* p = ws + o; o += (bytes + 255) & ~255ull; return p; };
  float*  rowmax = (float*)alloc((size_t)N * 4);
  uint*   deg0   = (uint*)alloc((size_t)N * 4);
  ushort* hT     = (ushort*)alloc((size_t)HID * N * 2);
  float*  es     = (float*)alloc((size_t)NH * N * 4);
  float*  ed     = (float*)alloc((size_t)NH * N * 4);
  float*  o_part = (float*)alloc((size_t)TSPLIT * N * HID * 4);
  float*  s_part = (float*)alloc((size_t)TSPLIT * N * NH * 4);

  dim3 gr(N / 32, TSPLIT);
  // node 1: hx layer0 + prep (rowmax/deg0) in one launch
  k_hx0p<<<N / 16 + N / 4, 256, 0, stream>>>(tmat, adj, emb, Ws, bs, gW, gA,
                                             hT, es, ed, rowmax, deg0);
  // node 2: att layer0
  k_att<<<gr, 256, 0, stream>>>(tmat, adj, rowmax, hT, es, ed, deg0, o_part, s_part);
  // node 3: hx layer1 (combine fused)
  k_hx1<<<N / 16, 256, 0, stream>>>(o_part, s_part, lng, lnb,
                                    gW + (size_t)NH * HID * HD, gA + (size_t)NH * 2 * HD,
                                    hT, es, ed);
  // node 4: att layer1
  k_att<<<gr, 256, 0, stream>>>(tmat, adj, rowmax, hT, es, ed, deg0, o_part, s_part);
  // node 5: final (combine fused)
  k_final<<<NB / 16, 256, 0, stream>>>(o_part, s_part, lng + HID, lnb + HID,
                                       topic_ids, attr, Wa, ba, W1, b1, W2, b2, (float*)d_out);
}